// Round 18
// baseline (156.114 us; speedup 1.0000x reference)
//
#include <hip/hip_runtime.h>
#include <hip/hip_bf16.h>
#include <math.h>

#define B_      16
#define NPUS    1024
#define MEMS    4096
#define INS     512
#define RS      256
#define MD      128
#define GRUIN   640
#define MMUO    644
#define NROWS   (B_*NPUS)   // 16384

// d_out flat offsets (reference return order)
#define O_OUT   0u
#define O_REGS  8388608u
#define O_WKEY  12582912u
#define O_WVAL  14680064u
#define O_WGATE 16777216u
#define O_SSDK  16793600u
#define O_SSDV  18890752u
#define O_SSDG  20987904u

typedef __attribute__((ext_vector_type(8))) short bf16x8;
typedef __attribute__((ext_vector_type(4))) float f32x4;
typedef __attribute__((ext_vector_type(4))) unsigned short u16x4;

__device__ __forceinline__ float sigf(float x){ return 1.f/(1.f+__expf(-x)); }
__device__ __forceinline__ unsigned short bfu(float x){
    __hip_bfloat16 h = __float2bfloat16(x);
    return __builtin_bit_cast(unsigned short, h);
}
__device__ __forceinline__ float b2f(unsigned short u){
    unsigned v = ((unsigned)u) << 16;
    return __builtin_bit_cast(float, v);
}
__device__ __forceinline__ float ex2(float x){
#if __has_builtin(__builtin_amdgcn_exp2f)
    return __builtin_amdgcn_exp2f(x);
#else
    return exp2f(x);
#endif
}
// async global->LDS, 16B per lane; LDS dest is wave-uniform base + lane*16 (m104)
__device__ __forceinline__ void gload16(const void* g, void* s)
{
    __builtin_amdgcn_global_load_lds(
        (const __attribute__((address_space(1))) void*)g,
        (__attribute__((address_space(3))) void*)s, 16, 0, 0);
}

// ---------------- K_cvt: fp32 -> bf16, vectorized x4 ----------------
__global__ __launch_bounds__(256) void k_cvt(const float* __restrict__ src,
                                             unsigned short* __restrict__ dst, int n4)
{
    int i = blockIdx.x*256 + threadIdx.x;
    if (i >= n4) return;
    float4 v = ((const float4*)src)[i];
    u16x4 o = { bfu(v.x), bfu(v.y), bfu(v.z), bfu(v.w) };
    ((u16x4*)dst)[i] = o;
}

// ---------------- K_cvt5g: fused 5-tensor fp32->bf16 + gi0 GEMM (blocks >= 969) ----------------
__global__ __launch_bounds__(256) void k_cvt5g(const float* __restrict__ s0, unsigned short* __restrict__ d0,
                                               const float* __restrict__ s1, unsigned short* __restrict__ d1,
                                               const float* __restrict__ s2, unsigned short* __restrict__ d2,
                                               const float* __restrict__ s3, unsigned short* __restrict__ d3,
                                               const float* __restrict__ s4, unsigned short* __restrict__ d4,
                                               float* __restrict__ gi0)
{
    __shared__ float xs[INS];
    if (blockIdx.x >= 969) {
        const int gb = blockIdx.x - 969;
        const int b = gb / 3, seg = gb % 3;
        const int t = threadIdx.x;
        for (int i = t; i < INS; i += 256) xs[i] = s4[(size_t)b*INS + i];
        __syncthreads();
        const int o = seg*256 + t;
        const float* wrow = s1 + (size_t)o*GRUIN;
        float a0 = 0.f, a1 = 0.f, a2 = 0.f, a3 = 0.f;
        for (int k = 0; k < INS; k += 4) {
            float4 wv = *(const float4*)(wrow + k);
            a0 += xs[k]*wv.x; a1 += xs[k+1]*wv.y; a2 += xs[k+2]*wv.z; a3 += xs[k+3]*wv.w;
        }
        gi0[(size_t)b*768 + o] = (a0 + a1) + (a2 + a3);
        return;
    }
    int gi = blockIdx.x*256 + threadIdx.x;
    const float* s; unsigned short* d; int idx;
    if      (gi < 41216)  { s = s0; d = d0; idx = gi; }
    else if (gi < 164096) { s = s1; d = d1; idx = gi - 41216; }
    else if (gi < 213248) { s = s2; d = d2; idx = gi - 164096; }
    else if (gi < 246016) { s = s3; d = d3; idx = gi - 213248; }
    else                  { s = s4; d = d4; idx = gi - 246016; }
    float4 v = ((const float4*)s)[idx];
    u16x4 o = { bfu(v.x), bfu(v.y), bfu(v.z), bfu(v.w) };
    ((u16x4*)d)[idx] = o;
}

// ---------------- K0: memory_context -> bf16 row-major + key-PERMUTED transposed ----------------
__global__ __launch_bounds__(256) void k_conv(const float* __restrict__ mem,
                                              __hip_bfloat16* __restrict__ memB,
                                              __hip_bfloat16* __restrict__ memT)
{
    __shared__ float Ms[32][129];
    const int t = threadIdx.x;
    const int b = blockIdx.x >> 7;
    const int m0 = (blockIdx.x & 127) << 5;
    const float* src = mem + ((size_t)b*MEMS + m0)*MD;
    for (int idx = t; idx < 32*128; idx += 256) {
        int m = idx >> 7, d = idx & 127;
        float v = src[(size_t)m*MD + d];
        Ms[m][d] = v;
        memB[((size_t)b*MEMS + m0 + m)*MD + d] = __float2bfloat16(v);
    }
    __syncthreads();
    for (int idx = t; idx < 128*32; idx += 256) {
        int d = idx >> 5, m = idx & 31;
        int pos = (m < 16) ? (2*m) : (2*(m-16)+1);
        memT[((size_t)b*MD + d)*MEMS + m0 + pos] = __float2bfloat16(Ms[m][d]);
    }
}

// ---------------- K1: MMU GEMM (MFMA, LDS-staged, 128-col tiles, fused ssd softmax) ----------------
// qbf pre-scaled by log2(e)/sqrt(128): scores arrive in log2 domain for exp2 softmax.
__global__ __launch_bounds__(256, 4) void k_mmu(const __hip_bfloat16* __restrict__ Ab,
                                                const __hip_bfloat16* __restrict__ Wb,
                                                const float* __restrict__ bias,
                                                float* __restrict__ out,
                                                __hip_bfloat16* __restrict__ qbf)
{
    __shared__ __hip_bfloat16 At[2][64][32];
    __shared__ __hip_bfloat16 Bt[2][128][32];
    const int t = threadIdx.x, w = t >> 6, l = t & 63;
    const int lg = l >> 4, ll = l & 15;
    const int m0 = blockIdx.x*64;
    const int n0 = blockIdx.y*128;
    f32x4 acc[8];
    #pragma unroll
    for (int c = 0; c < 8; c++) acc[c] = (f32x4){0,0,0,0};

    const char* aSrc;
    {
        int row = t >> 2, cc = t & 3;
        int gc = cc ^ ((row >> 1) & 3);
        aSrc = (const char*)((const short*)Ab + (size_t)(m0+row)*RS) + gc*16;
    }
    const char* bSrc[2];
    #pragma unroll
    for (int j = 0; j < 2; j++) {
        int ci = w*128 + j*64 + l;
        int row = ci >> 2, cc = ci & 3;
        int gc = cc ^ ((row >> 1) & 3);
        bSrc[j] = (const char*)((const short*)Wb + (size_t)(n0+row)*RS) + gc*16;
    }

    auto stage = [&](int buf, int it) {
        int off = it*64;
        char* abase = (char*)(&At[buf][0][0]) + (size_t)(w << 6)*16;
        gload16(aSrc + off, abase);
        #pragma unroll
        for (int j = 0; j < 2; j++) {
            char* bbase = (char*)(&Bt[buf][0][0]) + (size_t)(w*128 + j*64)*16;
            gload16(bSrc[j] + off, bbase);
        }
    };

    stage(0, 0);
    asm volatile("s_waitcnt vmcnt(0)" ::: "memory");
    __syncthreads();
    int cur = 0;
    const int arow = (w << 4) + ll;
    const int aswz = ((lg ^ ((arow >> 1) & 3)) << 4);
    for (int it = 0; it < 8; ++it) {
        if (it + 1 < 8) stage(cur ^ 1, it + 1);
        const char* ab = (const char*)(&At[cur][0][0]);
        const char* bb = (const char*)(&Bt[cur][0][0]);
        bf16x8 af = *(const bf16x8*)(ab + arow*64 + aswz);
        #pragma unroll
        for (int c = 0; c < 8; c++) {
            int r0 = c*16 + ll;
            int sw = ((lg ^ ((r0 >> 1) & 3)) << 4);
            bf16x8 bf = *(const bf16x8*)(bb + (size_t)r0*64 + sw);
            acc[c] = __builtin_amdgcn_mfma_f32_16x16x32_bf16(af, bf, acc[c], 0, 0, 0);
        }
        asm volatile("s_waitcnt vmcnt(0)" ::: "memory");
        __syncthreads();
        cur ^= 1;
    }
    const int wm0 = m0 + (w << 4);
    const float QSCL = 0.08838834764831845f * 1.4426950408889634f;  // /sqrt(128) * log2(e)
    #pragma unroll
    for (int c = 0; c < 8; c++) {
        int o = n0 + c*16 + ll;
        if (o > 640) continue;
        float bv = bias[o];
        #pragma unroll
        for (int r = 0; r < 4; r++) {
            int row = wm0 + lg*4 + r;
            float v = acc[c][r] + bv;
            if      (o < MD)        qbf[(size_t)row*MD + o] = __float2bfloat16(v * QSCL);
            else if (o < 2*MD)      out[O_WKEY + (size_t)row*MD + (o -   MD)] = v;
            else if (o < 3*MD)      out[O_WVAL + (size_t)row*MD + (o - 2*MD)] = v;
            else if (o == 3*MD)     out[O_WGATE + row] = sigf(v);
            else if (o < 4*MD + 1)  out[O_SSDK + (size_t)row*MD + (o - (3*MD+1))] = v;
            else                    out[O_SSDV + (size_t)row*MD + (o - (4*MD+1))] = v;
        }
    }
    if (n0 == 640) {
        #pragma unroll
        for (int r = 0; r < 4; r++) {
            int o = n0 + ll;
            float vr = acc[0][r] + ((o < MMUO) ? bias[o] : 0.f);
            float va = __shfl(vr, lg*16 + 1);
            float vb = __shfl(vr, lg*16 + 2);
            float vc = __shfl(vr, lg*16 + 3);
            float mm = fmaxf(va, fmaxf(vb, vc));
            float ea = __expf(va-mm), eb = __expf(vb-mm), ec = __expf(vc-mm);
            float inv = 1.f/(ea+eb+ec);
            int row = wm0 + lg*4 + r;
            if (ll == 1) out[O_SSDG + (size_t)row*3 + 0] = ea*inv;
            if (ll == 2) out[O_SSDG + (size_t)row*3 + 1] = eb*inv;
            if (ll == 3) out[O_SSDG + (size_t)row*3 + 2] = ec*inv;
        }
    }
}

// ---------------- K2: LDS-staged 4-way split-K flash attention, 32 q-rows/wave ----------------
// Triple-buffered (one s_barrier per iter: vmcnt(4) -> barrier -> stage(it+2) ->
// compute(it)); exp2-domain softmax (Q pre-scaled by log2e). launch_bounds(256,2)
// (no spill; round-16 lesson). Packed P b32 stores match permuted memT key order.
__global__ __launch_bounds__(256, 2) void k_attn(const __hip_bfloat16* __restrict__ qb,
                                                 const __hip_bfloat16* __restrict__ memB,
                                                 const __hip_bfloat16* __restrict__ memT,
                                                 unsigned short* __restrict__ Opart,
                                                 float* __restrict__ MLpart)
{
    __shared__ __hip_bfloat16 Kt[3][32][128];
    __shared__ __hip_bfloat16 Vt[3][128][32];
    __shared__ unsigned int Pl32[4][16][20];   // 80B rows
    const int t = threadIdx.x, w = t >> 6, l = t & 63;
    const int lg = l >> 4, ll = l & 15;
    const int bid = blockIdx.x;
    const int xcd = bid & 7, rest = bid >> 3;      // rest 0..63
    const int b = xcd + ((rest >> 5) << 3);        // 2 batches per XCD
    const int sub = rest & 31;
    const int qblk = sub >> 2, kh = sub & 3;       // 8 q-groups x 4 key-quarters
    const int qrow0 = (b << 10) + (qblk << 7) + (w << 5);   // wave's 32 q-rows
    const int k_beg = kh << 10;                             // 1024 keys per quarter
    const float THR = 5.77f;                       // log2 domain (~= 4 nats)

    const short* Q = (const short*)qb;
    bf16x8 qf[2][4];
    #pragma unroll
    for (int qs = 0; qs < 2; qs++)
        #pragma unroll
        for (int ks = 0; ks < 4; ks++)
            qf[qs][ks] = *(const bf16x8*)(Q + (size_t)(qrow0 + qs*16 + ll)*MD + ks*32 + lg*8);

    f32x4 O[2][8];
    #pragma unroll
    for (int qs = 0; qs < 2; qs++)
        #pragma unroll
        for (int dt = 0; dt < 8; dt++) O[qs][dt] = (f32x4){0.f,0.f,0.f,0.f};
    float m_run[2][4], lsum[2][4];
    #pragma unroll
    for (int qs = 0; qs < 2; qs++)
        #pragma unroll
        for (int r = 0; r < 4; r++) { m_run[qs][r] = -INFINITY; lsum[qs][r] = 0.f; }

    const char* MbB = (const char*)memB + (size_t)b*MEMS*MD*2;
    const char* MtB = (const char*)memT + (size_t)b*MD*MEMS*2;

    auto stage = [&](int buf, int it) {
        const int k0 = k_beg + it*32;
        char* kbase = (char*)(&Kt[buf][0][0]);
        char* vbase = (char*)(&Vt[buf][0][0]);
        #pragma unroll
        for (int j = 0; j < 2; j++) {
            int ci = (w << 7) + (j << 6) + l;        // chunk 0..511 (16B each)
            int krow = ci >> 4, cc = ci & 15;
            int gc = cc ^ (krow & 7);                // pre-swizzled global source
            gload16(MbB + (size_t)(k0 + krow)*256 + gc*16,
                    kbase + (size_t)((w << 7) + (j << 6))*16);
        }
        #pragma unroll
        for (int j = 0; j < 2; j++) {
            int ci = (w << 7) + (j << 6) + l;
            int drow = ci >> 2, cc = ci & 3;
            int gc = cc ^ ((drow >> 1) & 3);         // V swizzle (both-sides involution)
            gload16(MtB + (size_t)drow*(MEMS*2) + (size_t)k0*2 + gc*16,
                    vbase + (size_t)((w << 7) + (j << 6))*16);
        }
    };

    const int NIT = 1024/32;   // 32
    stage(0, 0);
    stage(1, 1);
    int cur = 0;
    const int vsw = ((lg ^ ((ll >> 1) & 3)) << 4);
    for (int it = 0; it < NIT; ++it) {
        if (it < NIT-1) { asm volatile("s_waitcnt vmcnt(4)" ::: "memory"); }
        else            { asm volatile("s_waitcnt vmcnt(0)" ::: "memory"); }
        asm volatile("s_barrier" ::: "memory");    // all waves' stage(it) landed;
                                                   // all compute(it-1) done
        int st = cur + 2; if (st >= 3) st -= 3;
        if (it + 2 < NIT) stage(st, it + 2);
        const char* kbase = (const char*)(&Kt[cur][0][0]);
        const char* vbase = (const char*)(&Vt[cur][0][0]);
        // V fragments once per iter, reused for both q-halves
        bf16x8 vf[8];
        #pragma unroll
        for (int dt = 0; dt < 8; dt++)
            vf[dt] = *(const bf16x8*)(vbase + (size_t)(dt*16 + ll)*64 + vsw);
        // QK^T for both q-halves from one K-frag read
        f32x4 s[2][2];
        s[0][0]=(f32x4){0,0,0,0}; s[0][1]=(f32x4){0,0,0,0};
        s[1][0]=(f32x4){0,0,0,0}; s[1][1]=(f32x4){0,0,0,0};
        #pragma unroll
        for (int ks = 0; ks < 4; ks++) {
            int c0 = ks*4 + lg;
            int sw = (c0 ^ (ll & 7)) << 4;
            bf16x8 kf0 = *(const bf16x8*)(kbase + (size_t)ll*256 + sw);
            bf16x8 kf1 = *(const bf16x8*)(kbase + (size_t)(16 + ll)*256 + sw);
            s[0][0] = __builtin_amdgcn_mfma_f32_16x16x32_bf16(qf[0][ks], kf0, s[0][0], 0, 0, 0);
            s[1][0] = __builtin_amdgcn_mfma_f32_16x16x32_bf16(qf[1][ks], kf0, s[1][0], 0, 0, 0);
            s[0][1] = __builtin_amdgcn_mfma_f32_16x16x32_bf16(qf[0][ks], kf1, s[0][1], 0, 0, 0);
            s[1][1] = __builtin_amdgcn_mfma_f32_16x16x32_bf16(qf[1][ks], kf1, s[1][1], 0, 0, 0);
        }
        // defer-max (fast path: no cross-lane ops)
        bool need = false;
        #pragma unroll
        for (int qs = 0; qs < 2; qs++)
            #pragma unroll
            for (int r = 0; r < 4; r++) {
                need |= (s[qs][0][r] > m_run[qs][r] + THR);
                need |= (s[qs][1][r] > m_run[qs][r] + THR);
            }
        if (__any(need)) {
            #pragma unroll
            for (int qs = 0; qs < 2; qs++)
                #pragma unroll
                for (int r = 0; r < 4; r++) {
                    float v = fmaxf(s[qs][0][r], s[qs][1][r]);
                    v = fmaxf(v, __shfl_xor(v, 1));
                    v = fmaxf(v, __shfl_xor(v, 2));
                    v = fmaxf(v, __shfl_xor(v, 4));
                    v = fmaxf(v, __shfl_xor(v, 8));
                    float mnew = fmaxf(m_run[qs][r], v);
                    float alpha = ex2(m_run[qs][r] - mnew);
                    m_run[qs][r] = mnew;
                    lsum[qs][r] *= alpha;
                    #pragma unroll
                    for (int dt = 0; dt < 8; dt++) O[qs][dt][r] *= alpha;
                }
        }
        // P (packed u32 pairs, exp2) + PV per q-half
        #pragma unroll
        for (int qs = 0; qs < 2; qs++) {
            #pragma unroll
            for (int r = 0; r < 4; r++) {
                float p0 = ex2(s[qs][0][r] - m_run[qs][r]);
                float p1 = ex2(s[qs][1][r] - m_run[qs][r]);
                Pl32[w][lg*4 + r][ll] = (unsigned)bfu(p0) | ((unsigned)bfu(p1) << 16);
                lsum[qs][r] += p0 + p1;
            }
            __builtin_amdgcn_wave_barrier();
            bf16x8 pa = *(const bf16x8*)((const char*)(&Pl32[w][0][0]) + (size_t)ll*80 + lg*16);
            __builtin_amdgcn_wave_barrier();
            #pragma unroll
            for (int dt = 0; dt < 8; dt++)
                O[qs][dt] = __builtin_amdgcn_mfma_f32_16x16x32_bf16(pa, vf[dt], O[qs][dt], 0, 0, 0);
        }
        cur = (cur + 1 == 3) ? 0 : cur + 1;
    }
    #pragma unroll
    for (int qs = 0; qs < 2; qs++)
        #pragma unroll
        for (int r = 0; r < 4; r++) {
            float s2 = lsum[qs][r];
            s2 += __shfl_xor(s2, 1);
            s2 += __shfl_xor(s2, 2);
            s2 += __shfl_xor(s2, 4);
            s2 += __shfl_xor(s2, 8);
            lsum[qs][r] = s2;
        }
    #pragma unroll
    for (int qs = 0; qs < 2; qs++)
        #pragma unroll
        for (int dt = 0; dt < 8; dt++)
            #pragma unroll
            for (int r = 0; r < 4; r++) {
                int row = qrow0 + qs*16 + lg*4 + r;
                Opart[((size_t)row*4 + kh)*128 + dt*16 + ll] = bfu(O[qs][dt][r]);
            }
    if (ll == 0) {
        #pragma unroll
        for (int qs = 0; qs < 2; qs++)
            #pragma unroll
            for (int r = 0; r < 4; r++) {
                int row = qrow0 + qs*16 + lg*4 + r;
                MLpart[((size_t)row*4 + kh)*2 + 0] = m_run[qs][r];   // log2 domain
                MLpart[((size_t)row*4 + kh)*2 + 1] = lsum[qs][r];
            }
    }
}

// ---------------- K2b: combine the 4 split-K partials (bf16) -> rd bf16 ----------------
__global__ __launch_bounds__(256) void k_comb(const unsigned short* __restrict__ Opart,
                                              const float* __restrict__ MLpart,
                                              __hip_bfloat16* __restrict__ rdb)
{
    const int t = threadIdx.x;
    const int row = blockIdx.x*64 + (t >> 2);
    const int c0 = (t & 3) * 32;
    float m[4], lv[4], a[4];
    float M = -INFINITY;
    #pragma unroll
    for (int i = 0; i < 4; i++) {
        m[i]  = MLpart[((size_t)row*4 + i)*2 + 0];
        lv[i] = MLpart[((size_t)row*4 + i)*2 + 1];
        M = fmaxf(M, m[i]);
    }
    float L = 0.f;
    #pragma unroll
    for (int i = 0; i < 4; i++) { a[i] = ex2(m[i] - M); L += a[i]*lv[i]; }   // log2 domain
    float invL = 1.f / L;
    #pragma unroll
    for (int i = 0; i < 4; i++) a[i] *= invL;
    unsigned short* dst = (unsigned short*)rdb + (size_t)row*128 + c0;
    #pragma unroll
    for (int j = 0; j < 8; j++) {
        float acc0=0.f, acc1=0.f, acc2=0.f, acc3=0.f;
        #pragma unroll
        for (int i = 0; i < 4; i++) {
            u16x4 x = ((const u16x4*)(Opart + ((size_t)row*4 + i)*128 + c0))[j];
            acc0 += a[i]*b2f(x[0]); acc1 += a[i]*b2f(x[1]);
            acc2 += a[i]*b2f(x[2]); acc3 += a[i]*b2f(x[3]);
        }
        u16x4 o = { bfu(acc0), bfu(acc1), bfu(acc2), bfu(acc3) };
        ((u16x4*)dst)[j] = o;
    }
}

// ---------------- K3: fused GRU (MFMA, LDS-staged, gi0-precomputed) ----------------
__global__ __launch_bounds__(256, 4) void k_gru(const float* __restrict__ gi0,
                                                const __hip_bfloat16* __restrict__ rdb,
                                                const __hip_bfloat16* __restrict__ regsb,
                                                const float* __restrict__ regs,
                                                const __hip_bfloat16* __restrict__ Wihb,
                                                const float* __restrict__ bih,
                                                const __hip_bfloat16* __restrict__ Whhb,
                                                const float* __restrict__ bhh,
                                                float* __restrict__ newregs,
                                                __hip_bfloat16* __restrict__ nregsb)
{
    __shared__ __hip_bfloat16 At[2][64][32];
    __shared__ __hip_bfloat16 Bt[2][192][32];
    const int t = threadIdx.x, w = t >> 6, l = t & 63;
    const int lg = l >> 4, ll = l & 15;
    const int m0 = blockIdx.x*64;
    const int n0 = blockIdx.y*64;
    const int batch = blockIdx.x >> 4;
    const short* Rd = (const short*)rdb;
    const short* Hb = (const short*)regsb;
    const short* Wi = (const short*)Wihb;
    const short* Wh = (const short*)Whhb;

    f32x4 aR[4], aZ[4], aNi[4], aNh[4];
    #pragma unroll
    for (int c = 0; c < 4; c++) {
        int o = n0 + c*16 + ll;
        float gR = gi0[(size_t)batch*768 + o];
        float gZ = gi0[(size_t)batch*768 + 256 + o];
        float gN = gi0[(size_t)batch*768 + 512 + o];
        aR[c]  = (f32x4){gR,gR,gR,gR};
        aZ[c]  = (f32x4){gZ,gZ,gZ,gZ};
        aNi[c] = (f32x4){gN,gN,gN,gN};
        aNh[c] = (f32x4){0,0,0,0};
    }

    const int aci = (w << 6) + l;
    const int arow_s = aci >> 2, acc_s = aci & 3;
    const int agc = acc_s ^ ((arow_s >> 1) & 3);
    const char* aSrcA = (const char*)(Rd + (size_t)(m0+arow_s)*MD) + agc*16;
    const char* aSrcB = (const char*)(Hb + (size_t)(m0+arow_s)*RS) + agc*16;
    const char* bSrcA0; const char* bSrcA1; const char* bSrcA2;
    const char* bSrcB0; const char* bSrcB1; const char* bSrcB2;
    {
        int ci, row, cc, gc, g, col;
        ci = w*192 + 0*64 + l; row = ci >> 2; cc = ci & 3; gc = cc ^ ((row >> 1) & 3);
        g = row >> 6; col = row & 63;
        bSrcA0 = (const char*)(Wi + (size_t)(g*RS + n0 + col)*GRUIN + INS) + gc*16;
        bSrcB0 = (const char*)(Wh + (size_t)(g*RS + n0 + col)*RS) + gc*16;
        ci = w*192 + 1*64 + l; row = ci >> 2; cc = ci & 3; gc = cc ^ ((row >> 1) & 3);
        g = row >> 6; col = row & 63;
        bSrcA1 = (const char*)(Wi + (size_t)(g*RS + n0 + col)*GRUIN + INS) + gc*16;
        bSrcB1 = (const char*)(Wh + (size_t)(g*RS + n0 + col)*RS) + gc*16;
        ci = w*192 + 2*64 + l; row = ci >> 2; cc = ci & 3; gc = cc ^ ((row >> 1) & 3);
        g = row >> 6; col = row & 63;
        bSrcA2 = (const char*)(Wi + (size_t)(g*RS + n0 + col)*GRUIN + INS) + gc*16;
        bSrcB2 = (const char*)(Wh + (size_t)(g*RS + n0 + col)*RS) + gc*16;
    }

    const int NITA = 4, NIT = 12;
    auto stage = [&](int buf, int it) {
        char* abase = (char*)(&At[buf][0][0]) + (size_t)(w << 6)*16;
        char* bbase = (char*)(&Bt[buf][0][0]) + (size_t)(w*192)*16;
        const char *as, *b0, *b1, *b2;
        if (it < NITA) {
            int off = it*64;
            as = aSrcA + off; b0 = bSrcA0 + off; b1 = bSrcA1 + off; b2 = bSrcA2 + off;
        } else {
            int off = (it - NITA)*64;
            as = aSrcB + off; b0 = bSrcB0 + off; b1 = bSrcB1 + off; b2 = bSrcB2 + off;
        }
        gload16(as, abase);
        gload16(b0, bbase);
        gload16(b1, bbase + 64*16);
        gload16(b2, bbase + 128*16);
    };

    stage(0, 0);
    asm volatile("s_waitcnt vmcnt(0)" ::: "memory");
    __syncthreads();
    int cur = 0;
    const int arow = (w << 4) + ll;
    const int aswz = ((lg ^ ((arow >> 1) & 3)) << 4);
    for (int it = 0; it < NIT; ++it) {
        if (it + 1 < NIT) stage(cur ^ 1, it + 1);
        const char* ab = (const char*)(&At[cur][0][0]);
        const char* bb = (const char*)(&Bt[cur][0][0]);
        bf16x8 af = *(const bf16x8*)(ab + arow*64 + aswz);
        if (it < NITA) {
            #pragma unroll
            for (int c = 0; c < 4; c++) {
                int r0 = c*16 + ll;
                int sw = ((lg ^ ((r0 >> 1) & 3)) << 4);
                bf16x8 bR = *(const bf16x8*)(bb + (size_t)r0*64 + sw);
                bf16x8 bZ = *(const bf16x8*)(bb + (size_t)(r0 + 64)*64 + sw);
                bf16x8 bN = *(const bf16x8*)(bb + (size_t)(r0 + 128)*64 + sw);
                aR[c]  = __builtin_amdgcn_mfma_f32_16x16x32_bf16(af, bR, aR[c],  0, 0, 0);
                aZ[c]  = __builtin_amdgcn_mfma_f32_16x16x32_bf16(af, bZ, aZ[c],  0, 0, 0);
                aNi[c] = __builtin_amdgcn_mfma_f32_16x16x32_bf16(af, bN, aNi[c], 0, 0, 0);
            }
        } else {
            #pragma unroll
            for (int c = 0; c < 4; c++) {
                int r0 = c*16 + ll;
                int sw = ((lg ^ ((r0 >> 1) & 3)) << 4);
                bf16x8 bR = *(const bf16x8*)(bb + (size_t)r0*64 + sw);
                bf16x8 bZ = *(const bf16x8*)(bb + (size_t)(r0 + 64)*64 + sw);
                bf16x8 bN = *(const bf16x8*)(bb + (size_t)(r0 + 128)*64 + sw);
                aR[c]  = __builtin_amdgcn_mfma_f32_16x16x32_bf16(af, bR, aR[c],  0, 0, 0);
                aZ[c]  = __builtin_amdgcn_mfma_f32_16x16x32_bf16(af, bZ, aZ[c],  0, 0, 0);
                aNh[c] = __builtin_amdgcn_mfma_f32_16x16x32_bf16(af, bN, aNh[c], 0, 0, 0);
            }
        }
        asm volatile("s_waitcnt vmcnt(0)" ::: "memory");
        __syncthreads();
        cur ^= 1;
    }
    const int wm0 = m0 + (w << 4);
    #pragma unroll
    for (int c = 0; c < 4; c++) {
        int o = n0 + c*16 + ll;
        float bR = bih[o]        + bhh[o];
        float bZ = bih[o +   RS] + bhh[o +   RS];
        float bNi = bih[o + 2*RS];
        float bNh = bhh[o + 2*RS];
        #pragma unroll
        for (int r = 0; r < 4; r++) {
            int row = wm0 + lg*4 + r;
            float rr = sigf(aR[c][r] + bR);
            float zz = sigf(aZ[c][r] + bZ);
            float nn = tanhf(aNi[c][r] + bNi + rr*(aNh[c][r] + bNh));
            float cv = regs[(size_t)row*RS + o];
            float nv = (1.f - zz)*nn + zz*cv;
            newregs[(size_t)row*RS + o] = nv;
            nregsb[(size_t)row*RS + o] = __float2bfloat16(nv);
        }
    }
}

// ---------------- K4: output GEMM (MFMA, LDS-staged, 128-col tiles) ----------------
__global__ __launch_bounds__(256, 4) void k_out(const __hip_bfloat16* __restrict__ Ab,
                                                const __hip_bfloat16* __restrict__ Wb,
                                                const float* __restrict__ bias,
                                                float* __restrict__ out0)
{
    __shared__ __hip_bfloat16 At[2][64][32];
    __shared__ __hip_bfloat16 Bt[2][128][32];
    const int t = threadIdx.x, w = t >> 6, l = t & 63;
    const int lg = l >> 4, ll = l & 15;
    const int m0 = blockIdx.x*64;
    const int n0 = blockIdx.y*128;
    f32x4 acc[8];
    #pragma unroll
    for (int c = 0; c < 8; c++) acc[c] = (f32x4){0,0,0,0};

    const char* aSrc;
    {
        int row = t >> 2, cc = t & 3;
        int gc = cc ^ ((row >> 1) & 3);
        aSrc = (const char*)((const short*)Ab + (size_t)(m0+row)*RS) + gc*16;
    }
    const char* bSrc[2];
    #pragma unroll
    for (int j = 0; j < 2; j++) {
        int ci = w*128 + j*64 + l;
        int row = ci >> 2, cc = ci & 3;
        int gc = cc ^ ((row >> 1) & 3);
        bSrc[j] = (const char*)((const short*)Wb + (size_t)(n0+row)*RS) + gc*16;
    }

    auto stage = [&](int buf, int it) {
        int off = it*64;
        char* abase = (char*)(&At[buf][0][0]) + (size_t)(w << 6)*16;
        gload16(aSrc + off, abase);
        #pragma unroll
        for (int j = 0; j < 2; j++) {
            char* bbase = (char*)(&Bt[buf][0][0]) + (size_t)(w*128 + j*64)*16;
            gload16(bSrc[j] + off, bbase);
        }
    };

    stage(0, 0);
    asm volatile("s_waitcnt vmcnt(0)" ::: "memory");
    __syncthreads();
    int cur = 0;
    const int arow = (w << 4) + ll;
    const int aswz = ((lg ^ ((arow >> 1) & 3)) << 4);
    for (int it = 0; it < 8; ++it) {
        if (it + 1 < 8) stage(cur ^ 1, it + 1);
        const char* ab = (const char*)(&At[cur][0][0]);
        const char* bb = (const char*)(&Bt[cur][0][0]);
        bf16x8 af = *(const bf16x8*)(ab + arow*64 + aswz);
        #pragma unroll
        for (int c = 0; c < 8; c++) {
            int r0 = c*16 + ll;
            int sw = ((lg ^ ((r0 >> 1) & 3)) << 4);
            bf16x8 bf = *(const bf16x8*)(bb + (size_t)r0*64 + sw);
            acc[c] = __builtin_amdgcn_mfma_f32_16x16x32_bf16(af, bf, acc[c], 0, 0, 0);
        }
        asm volatile("s_waitcnt vmcnt(0)" ::: "memory");
        __syncthreads();
        cur ^= 1;
    }
    const int wm0 = m0 + (w << 4);
    #pragma unroll
    for (int c = 0; c < 8; c++) {
        int o = n0 + c*16 + ll;
        float bv = bias[o];
        #pragma unroll
        for (int r = 0; r < 4; r++) {
            int row = wm0 + lg*4 + r;
            out0[(size_t)row*INS + o] = acc[c][r] + bv;
        }
    }
}

extern "C" void kernel_launch(void* const* d_in, const int* in_sizes, int n_in,
                              void* d_out, int out_size, void* d_ws, size_t ws_size,
                              hipStream_t stream)
{
    const float* inp  = (const float*)d_in[0];
    const float* regs = (const float*)d_in[1];
    const float* mem  = (const float*)d_in[2];
    const float* Wih  = (const float*)d_in[3];
    const float* bih  = (const float*)d_in[4];
    const float* Whh  = (const float*)d_in[5];
    const float* bhh  = (const float*)d_in[6];
    const float* Wmmu = (const float*)d_in[7];
    const float* bmmu = (const float*)d_in[8];
    const float* Wout = (const float*)d_in[9];
    const float* bout = (const float*)d_in[10];
    float* out = (float*)d_out;

    char* ws = (char*)d_ws;
    __hip_bfloat16* qbf    = (__hip_bfloat16*)(ws);
    __hip_bfloat16* rdb    = (__hip_bfloat16*)(ws + ((size_t)4<<20));
    __hip_bfloat16* memB   = (__hip_bfloat16*)(ws + ((size_t)8<<20));
    __hip_bfloat16* memT   = (__hip_bfloat16*)(ws + ((size_t)24<<20));
    __hip_bfloat16* regsb  = (__hip_bfloat16*)(ws + ((size_t)40<<20));
    __hip_bfloat16* nregsb = (__hip_bfloat16*)(ws + ((size_t)48<<20));
    __hip_bfloat16* Wmmub  = (__hip_bfloat16*)(ws + ((size_t)56<<20));
    __hip_bfloat16* Wihb   = (__hip_bfloat16*)(ws + ((size_t)56<<20) + ( 1<<20));
    __hip_bfloat16* Whhb   = (__hip_bfloat16*)(ws + ((size_t)56<<20) + ( 2<<20));
    __hip_bfloat16* Woutb  = (__hip_bfloat16*)(ws + ((size_t)56<<20) + ( 3<<20));
    __hip_bfloat16* inpb   = (__hip_bfloat16*)(ws + ((size_t)56<<20) + ( 4<<20));
    float*          MLpart = (float*)(ws + ((size_t)61<<20));            // 512 KB
    float*          gi0    = (float*)(ws + ((size_t)61<<20) + (1<<19));  // 49 KB
    unsigned short* Opart  = (unsigned short*)(out + O_OUT);  // 16.7 MB bf16 in out0 region

    k_cvt5g<<<1017, 256, 0, stream>>>(Wmmu, (unsigned short*)Wmmub,
                                      Wih,  (unsigned short*)Wihb,
                                      Whh,  (unsigned short*)Whhb,
                                      Wout, (unsigned short*)Woutb,
                                      inp,  (unsigned short*)inpb, gi0);
    k_cvt<<<(4194304/4 + 255)/256, 256, 0, stream>>>(regs, (unsigned short*)regsb, 4194304/4);
    k_conv<<<B_*128, 256, 0, stream>>>(mem, memB, memT);

    dim3 g1(NROWS/64, 6);
    k_mmu<<<g1, 256, 0, stream>>>(regsb, Wmmub, bmmu, out, qbf);
    k_attn<<<512, 256, 0, stream>>>(qbf, memB, memT, Opart, MLpart);
    k_comb<<<NROWS/64, 256, 0, stream>>>(Opart, MLpart, rdb);
    dim3 g3(NROWS/64, 4);
    k_gru<<<g3, 256, 0, stream>>>(gi0, rdb, regsb, regs, Wihb, bih, Whhb, bhh,
                                  out + O_REGS, nregsb);
    dim3 g4(NROWS/64, 4);
    k_out<<<g4, 256, 0, stream>>>(nregsb, Woutb, bout, out);
}

// Round 19
// 152.755 us; speedup vs baseline: 1.0220x; 1.0220x over previous
//
#include <hip/hip_runtime.h>
#include <hip/hip_bf16.h>
#include <math.h>

#define B_      16
#define NPUS    1024
#define MEMS    4096
#define INS     512
#define RS      256
#define MD      128
#define GRUIN   640
#define MMUO    644
#define NROWS   (B_*NPUS)   // 16384

// d_out flat offsets (reference return order)
#define O_OUT   0u
#define O_REGS  8388608u
#define O_WKEY  12582912u
#define O_WVAL  14680064u
#define O_WGATE 16777216u
#define O_SSDK  16793600u
#define O_SSDV  18890752u
#define O_SSDG  20987904u

typedef __attribute__((ext_vector_type(8))) short bf16x8;
typedef __attribute__((ext_vector_type(4))) float f32x4;
typedef __attribute__((ext_vector_type(4))) unsigned short u16x4;

__device__ __forceinline__ float sigf(float x){ return 1.f/(1.f+__expf(-x)); }
__device__ __forceinline__ unsigned short bfu(float x){
    __hip_bfloat16 h = __float2bfloat16(x);
    return __builtin_bit_cast(unsigned short, h);
}
__device__ __forceinline__ float b2f(unsigned short u){
    unsigned v = ((unsigned)u) << 16;
    return __builtin_bit_cast(float, v);
}
__device__ __forceinline__ float ex2(float x){
#if __has_builtin(__builtin_amdgcn_exp2f)
    return __builtin_amdgcn_exp2f(x);
#else
    return exp2f(x);
#endif
}
// async global->LDS, 16B per lane; LDS dest is wave-uniform base + lane*16 (m104)
__device__ __forceinline__ void gload16(const void* g, void* s)
{
    __builtin_amdgcn_global_load_lds(
        (const __attribute__((address_space(1))) void*)g,
        (__attribute__((address_space(3))) void*)s, 16, 0, 0);
}

// ---------------- K_cvt: fp32 -> bf16, vectorized x4 ----------------
__global__ __launch_bounds__(256) void k_cvt(const float* __restrict__ src,
                                             unsigned short* __restrict__ dst, int n4)
{
    int i = blockIdx.x*256 + threadIdx.x;
    if (i >= n4) return;
    float4 v = ((const float4*)src)[i];
    u16x4 o = { bfu(v.x), bfu(v.y), bfu(v.z), bfu(v.w) };
    ((u16x4*)dst)[i] = o;
}

// ---------------- K_cvt5g: fused 5-tensor fp32->bf16 + gi0 GEMM (blocks >= 969) ----------------
__global__ __launch_bounds__(256) void k_cvt5g(const float* __restrict__ s0, unsigned short* __restrict__ d0,
                                               const float* __restrict__ s1, unsigned short* __restrict__ d1,
                                               const float* __restrict__ s2, unsigned short* __restrict__ d2,
                                               const float* __restrict__ s3, unsigned short* __restrict__ d3,
                                               const float* __restrict__ s4, unsigned short* __restrict__ d4,
                                               float* __restrict__ gi0)
{
    __shared__ float xs[INS];
    if (blockIdx.x >= 969) {
        const int gb = blockIdx.x - 969;
        const int b = gb / 3, seg = gb % 3;
        const int t = threadIdx.x;
        for (int i = t; i < INS; i += 256) xs[i] = s4[(size_t)b*INS + i];
        __syncthreads();
        const int o = seg*256 + t;
        const float* wrow = s1 + (size_t)o*GRUIN;
        float a0 = 0.f, a1 = 0.f, a2 = 0.f, a3 = 0.f;
        for (int k = 0; k < INS; k += 4) {
            float4 wv = *(const float4*)(wrow + k);
            a0 += xs[k]*wv.x; a1 += xs[k+1]*wv.y; a2 += xs[k+2]*wv.z; a3 += xs[k+3]*wv.w;
        }
        gi0[(size_t)b*768 + o] = (a0 + a1) + (a2 + a3);
        return;
    }
    int gi = blockIdx.x*256 + threadIdx.x;
    const float* s; unsigned short* d; int idx;
    if      (gi < 41216)  { s = s0; d = d0; idx = gi; }
    else if (gi < 164096) { s = s1; d = d1; idx = gi - 41216; }
    else if (gi < 213248) { s = s2; d = d2; idx = gi - 164096; }
    else if (gi < 246016) { s = s3; d = d3; idx = gi - 213248; }
    else                  { s = s4; d = d4; idx = gi - 246016; }
    float4 v = ((const float4*)s)[idx];
    u16x4 o = { bfu(v.x), bfu(v.y), bfu(v.z), bfu(v.w) };
    ((u16x4*)d)[idx] = o;
}

// ---------------- K0: memory_context -> bf16 row-major + key-PERMUTED transposed ----------------
__global__ __launch_bounds__(256) void k_conv(const float* __restrict__ mem,
                                              __hip_bfloat16* __restrict__ memB,
                                              __hip_bfloat16* __restrict__ memT)
{
    __shared__ float Ms[32][129];
    const int t = threadIdx.x;
    const int b = blockIdx.x >> 7;
    const int m0 = (blockIdx.x & 127) << 5;
    const float* src = mem + ((size_t)b*MEMS + m0)*MD;
    for (int idx = t; idx < 32*128; idx += 256) {
        int m = idx >> 7, d = idx & 127;
        float v = src[(size_t)m*MD + d];
        Ms[m][d] = v;
        memB[((size_t)b*MEMS + m0 + m)*MD + d] = __float2bfloat16(v);
    }
    __syncthreads();
    for (int idx = t; idx < 128*32; idx += 256) {
        int d = idx >> 5, m = idx & 31;
        int pos = (m < 16) ? (2*m) : (2*(m-16)+1);
        memT[((size_t)b*MD + d)*MEMS + m0 + pos] = __float2bfloat16(Ms[m][d]);
    }
}

// ---------------- K1: MMU GEMM (MFMA, LDS-staged, 128-col tiles, fused ssd softmax) ----------------
// qbf pre-scaled by log2(e)/sqrt(128): scores arrive in log2 domain for exp2 softmax.
__global__ __launch_bounds__(256, 4) void k_mmu(const __hip_bfloat16* __restrict__ Ab,
                                                const __hip_bfloat16* __restrict__ Wb,
                                                const float* __restrict__ bias,
                                                float* __restrict__ out,
                                                __hip_bfloat16* __restrict__ qbf)
{
    __shared__ __hip_bfloat16 At[2][64][32];
    __shared__ __hip_bfloat16 Bt[2][128][32];
    const int t = threadIdx.x, w = t >> 6, l = t & 63;
    const int lg = l >> 4, ll = l & 15;
    const int m0 = blockIdx.x*64;
    const int n0 = blockIdx.y*128;
    f32x4 acc[8];
    #pragma unroll
    for (int c = 0; c < 8; c++) acc[c] = (f32x4){0,0,0,0};

    const char* aSrc;
    {
        int row = t >> 2, cc = t & 3;
        int gc = cc ^ ((row >> 1) & 3);
        aSrc = (const char*)((const short*)Ab + (size_t)(m0+row)*RS) + gc*16;
    }
    const char* bSrc[2];
    #pragma unroll
    for (int j = 0; j < 2; j++) {
        int ci = w*128 + j*64 + l;
        int row = ci >> 2, cc = ci & 3;
        int gc = cc ^ ((row >> 1) & 3);
        bSrc[j] = (const char*)((const short*)Wb + (size_t)(n0+row)*RS) + gc*16;
    }

    auto stage = [&](int buf, int it) {
        int off = it*64;
        char* abase = (char*)(&At[buf][0][0]) + (size_t)(w << 6)*16;
        gload16(aSrc + off, abase);
        #pragma unroll
        for (int j = 0; j < 2; j++) {
            char* bbase = (char*)(&Bt[buf][0][0]) + (size_t)(w*128 + j*64)*16;
            gload16(bSrc[j] + off, bbase);
        }
    };

    stage(0, 0);
    asm volatile("s_waitcnt vmcnt(0)" ::: "memory");
    __syncthreads();
    int cur = 0;
    const int arow = (w << 4) + ll;
    const int aswz = ((lg ^ ((arow >> 1) & 3)) << 4);
    for (int it = 0; it < 8; ++it) {
        if (it + 1 < 8) stage(cur ^ 1, it + 1);
        const char* ab = (const char*)(&At[cur][0][0]);
        const char* bb = (const char*)(&Bt[cur][0][0]);
        bf16x8 af = *(const bf16x8*)(ab + arow*64 + aswz);
        #pragma unroll
        for (int c = 0; c < 8; c++) {
            int r0 = c*16 + ll;
            int sw = ((lg ^ ((r0 >> 1) & 3)) << 4);
            bf16x8 bf = *(const bf16x8*)(bb + (size_t)r0*64 + sw);
            acc[c] = __builtin_amdgcn_mfma_f32_16x16x32_bf16(af, bf, acc[c], 0, 0, 0);
        }
        asm volatile("s_waitcnt vmcnt(0)" ::: "memory");
        __syncthreads();
        cur ^= 1;
    }
    const int wm0 = m0 + (w << 4);
    const float QSCL = 0.08838834764831845f * 1.4426950408889634f;  // /sqrt(128) * log2(e)
    #pragma unroll
    for (int c = 0; c < 8; c++) {
        int o = n0 + c*16 + ll;
        if (o > 640) continue;
        float bv = bias[o];
        #pragma unroll
        for (int r = 0; r < 4; r++) {
            int row = wm0 + lg*4 + r;
            float v = acc[c][r] + bv;
            if      (o < MD)        qbf[(size_t)row*MD + o] = __float2bfloat16(v * QSCL);
            else if (o < 2*MD)      out[O_WKEY + (size_t)row*MD + (o -   MD)] = v;
            else if (o < 3*MD)      out[O_WVAL + (size_t)row*MD + (o - 2*MD)] = v;
            else if (o == 3*MD)     out[O_WGATE + row] = sigf(v);
            else if (o < 4*MD + 1)  out[O_SSDK + (size_t)row*MD + (o - (3*MD+1))] = v;
            else                    out[O_SSDV + (size_t)row*MD + (o - (4*MD+1))] = v;
        }
    }
    if (n0 == 640) {
        #pragma unroll
        for (int r = 0; r < 4; r++) {
            int o = n0 + ll;
            float vr = acc[0][r] + ((o < MMUO) ? bias[o] : 0.f);
            float va = __shfl(vr, lg*16 + 1);
            float vb = __shfl(vr, lg*16 + 2);
            float vc = __shfl(vr, lg*16 + 3);
            float mm = fmaxf(va, fmaxf(vb, vc));
            float ea = __expf(va-mm), eb = __expf(vb-mm), ec = __expf(vc-mm);
            float inv = 1.f/(ea+eb+ec);
            int row = wm0 + lg*4 + r;
            if (ll == 1) out[O_SSDG + (size_t)row*3 + 0] = ea*inv;
            if (ll == 2) out[O_SSDG + (size_t)row*3 + 1] = eb*inv;
            if (ll == 3) out[O_SSDG + (size_t)row*3 + 2] = ec*inv;
        }
    }
}

// ---------------- K2: LDS-staged 4-way split-K flash attention, 32 q-rows/wave ----------------
// Round-17 double-buffered structure (best measured) + exp2-domain softmax.
// launch_bounds(256,2): 32q design is register-granule pinned at 2 waves/SIMD.
__global__ __launch_bounds__(256, 2) void k_attn(const __hip_bfloat16* __restrict__ qb,
                                                 const __hip_bfloat16* __restrict__ memB,
                                                 const __hip_bfloat16* __restrict__ memT,
                                                 unsigned short* __restrict__ Opart,
                                                 float* __restrict__ MLpart)
{
    __shared__ __hip_bfloat16 Kt[2][32][128];
    __shared__ __hip_bfloat16 Vt[2][128][32];
    __shared__ unsigned int Pl32[4][16][20];   // 80B rows
    const int t = threadIdx.x, w = t >> 6, l = t & 63;
    const int lg = l >> 4, ll = l & 15;
    const int bid = blockIdx.x;
    const int xcd = bid & 7, rest = bid >> 3;      // rest 0..63
    const int b = xcd + ((rest >> 5) << 3);        // 2 batches per XCD
    const int sub = rest & 31;
    const int qblk = sub >> 2, kh = sub & 3;       // 8 q-groups x 4 key-quarters
    const int qrow0 = (b << 10) + (qblk << 7) + (w << 5);   // wave's 32 q-rows
    const int k_beg = kh << 10;                             // 1024 keys per quarter
    const float THR = 5.77f;                       // log2 domain (~4 nats)

    const short* Q = (const short*)qb;
    bf16x8 qf[2][4];
    #pragma unroll
    for (int qs = 0; qs < 2; qs++)
        #pragma unroll
        for (int ks = 0; ks < 4; ks++)
            qf[qs][ks] = *(const bf16x8*)(Q + (size_t)(qrow0 + qs*16 + ll)*MD + ks*32 + lg*8);

    f32x4 O[2][8];
    #pragma unroll
    for (int qs = 0; qs < 2; qs++)
        #pragma unroll
        for (int dt = 0; dt < 8; dt++) O[qs][dt] = (f32x4){0.f,0.f,0.f,0.f};
    float m_run[2][4], lsum[2][4];
    #pragma unroll
    for (int qs = 0; qs < 2; qs++)
        #pragma unroll
        for (int r = 0; r < 4; r++) { m_run[qs][r] = -INFINITY; lsum[qs][r] = 0.f; }

    const char* MbB = (const char*)memB + (size_t)b*MEMS*MD*2;
    const char* MtB = (const char*)memT + (size_t)b*MD*MEMS*2;

    auto stage = [&](int buf, int it) {
        const int k0 = k_beg + it*32;
        char* kbase = (char*)(&Kt[buf][0][0]);
        char* vbase = (char*)(&Vt[buf][0][0]);
        #pragma unroll
        for (int j = 0; j < 2; j++) {
            int ci = (w << 7) + (j << 6) + l;        // chunk 0..511 (16B each)
            int krow = ci >> 4, cc = ci & 15;
            int gc = cc ^ (krow & 7);                // pre-swizzled global source
            gload16(MbB + (size_t)(k0 + krow)*256 + gc*16,
                    kbase + (size_t)((w << 7) + (j << 6))*16);
        }
        #pragma unroll
        for (int j = 0; j < 2; j++) {
            int ci = (w << 7) + (j << 6) + l;
            int drow = ci >> 2, cc = ci & 3;
            int gc = cc ^ ((drow >> 1) & 3);         // V swizzle (both-sides involution)
            gload16(MtB + (size_t)drow*(MEMS*2) + (size_t)k0*2 + gc*16,
                    vbase + (size_t)((w << 7) + (j << 6))*16);
        }
    };

    stage(0, 0);
    asm volatile("s_waitcnt vmcnt(0)" ::: "memory");
    asm volatile("s_barrier" ::: "memory");
    int cur = 0;
    const int NIT = 1024/32;   // 32
    const int vsw = ((lg ^ ((ll >> 1) & 3)) << 4);
    for (int it = 0; it < NIT; ++it) {
        if (it + 1 < NIT) {
            stage(cur ^ 1, it + 1);
            asm volatile("s_waitcnt vmcnt(4)" ::: "memory");
        } else {
            asm volatile("s_waitcnt vmcnt(0)" ::: "memory");
        }
        asm volatile("s_barrier" ::: "memory");
        const char* kbase = (const char*)(&Kt[cur][0][0]);
        const char* vbase = (const char*)(&Vt[cur][0][0]);
        // V fragments once per iter, reused for both q-halves
        bf16x8 vf[8];
        #pragma unroll
        for (int dt = 0; dt < 8; dt++)
            vf[dt] = *(const bf16x8*)(vbase + (size_t)(dt*16 + ll)*64 + vsw);
        // QK^T for both q-halves from one K-frag read
        f32x4 s[2][2];
        s[0][0]=(f32x4){0,0,0,0}; s[0][1]=(f32x4){0,0,0,0};
        s[1][0]=(f32x4){0,0,0,0}; s[1][1]=(f32x4){0,0,0,0};
        #pragma unroll
        for (int ks = 0; ks < 4; ks++) {
            int c0 = ks*4 + lg;
            int sw = (c0 ^ (ll & 7)) << 4;
            bf16x8 kf0 = *(const bf16x8*)(kbase + (size_t)ll*256 + sw);
            bf16x8 kf1 = *(const bf16x8*)(kbase + (size_t)(16 + ll)*256 + sw);
            s[0][0] = __builtin_amdgcn_mfma_f32_16x16x32_bf16(qf[0][ks], kf0, s[0][0], 0, 0, 0);
            s[1][0] = __builtin_amdgcn_mfma_f32_16x16x32_bf16(qf[1][ks], kf0, s[1][0], 0, 0, 0);
            s[0][1] = __builtin_amdgcn_mfma_f32_16x16x32_bf16(qf[0][ks], kf1, s[0][1], 0, 0, 0);
            s[1][1] = __builtin_amdgcn_mfma_f32_16x16x32_bf16(qf[1][ks], kf1, s[1][1], 0, 0, 0);
        }
        // defer-max (fast path: no cross-lane ops)
        bool need = false;
        #pragma unroll
        for (int qs = 0; qs < 2; qs++)
            #pragma unroll
            for (int r = 0; r < 4; r++) {
                need |= (s[qs][0][r] > m_run[qs][r] + THR);
                need |= (s[qs][1][r] > m_run[qs][r] + THR);
            }
        if (__any(need)) {
            #pragma unroll
            for (int qs = 0; qs < 2; qs++)
                #pragma unroll
                for (int r = 0; r < 4; r++) {
                    float v = fmaxf(s[qs][0][r], s[qs][1][r]);
                    v = fmaxf(v, __shfl_xor(v, 1));
                    v = fmaxf(v, __shfl_xor(v, 2));
                    v = fmaxf(v, __shfl_xor(v, 4));
                    v = fmaxf(v, __shfl_xor(v, 8));
                    float mnew = fmaxf(m_run[qs][r], v);
                    float alpha = ex2(m_run[qs][r] - mnew);
                    m_run[qs][r] = mnew;
                    lsum[qs][r] *= alpha;
                    #pragma unroll
                    for (int dt = 0; dt < 8; dt++) O[qs][dt][r] *= alpha;
                }
        }
        // P (packed u32 pairs, exp2) + PV per q-half
        #pragma unroll
        for (int qs = 0; qs < 2; qs++) {
            #pragma unroll
            for (int r = 0; r < 4; r++) {
                float p0 = ex2(s[qs][0][r] - m_run[qs][r]);
                float p1 = ex2(s[qs][1][r] - m_run[qs][r]);
                Pl32[w][lg*4 + r][ll] = (unsigned)bfu(p0) | ((unsigned)bfu(p1) << 16);
                lsum[qs][r] += p0 + p1;
            }
            __builtin_amdgcn_wave_barrier();
            bf16x8 pa = *(const bf16x8*)((const char*)(&Pl32[w][0][0]) + (size_t)ll*80 + lg*16);
            __builtin_amdgcn_wave_barrier();
            #pragma unroll
            for (int dt = 0; dt < 8; dt++)
                O[qs][dt] = __builtin_amdgcn_mfma_f32_16x16x32_bf16(pa, vf[dt], O[qs][dt], 0, 0, 0);
        }
        asm volatile("s_barrier" ::: "memory");
        cur ^= 1;
    }
    #pragma unroll
    for (int qs = 0; qs < 2; qs++)
        #pragma unroll
        for (int r = 0; r < 4; r++) {
            float s2 = lsum[qs][r];
            s2 += __shfl_xor(s2, 1);
            s2 += __shfl_xor(s2, 2);
            s2 += __shfl_xor(s2, 4);
            s2 += __shfl_xor(s2, 8);
            lsum[qs][r] = s2;
        }
    #pragma unroll
    for (int qs = 0; qs < 2; qs++)
        #pragma unroll
        for (int dt = 0; dt < 8; dt++)
            #pragma unroll
            for (int r = 0; r < 4; r++) {
                int row = qrow0 + qs*16 + lg*4 + r;
                Opart[((size_t)row*4 + kh)*128 + dt*16 + ll] = bfu(O[qs][dt][r]);
            }
    if (ll == 0) {
        #pragma unroll
        for (int qs = 0; qs < 2; qs++)
            #pragma unroll
            for (int r = 0; r < 4; r++) {
                int row = qrow0 + qs*16 + lg*4 + r;
                MLpart[((size_t)row*4 + kh)*2 + 0] = m_run[qs][r];   // log2 domain
                MLpart[((size_t)row*4 + kh)*2 + 1] = lsum[qs][r];
            }
    }
}

// ---------------- K2b: combine the 4 split-K partials (bf16) -> rd bf16 ----------------
__global__ __launch_bounds__(256) void k_comb(const unsigned short* __restrict__ Opart,
                                              const float* __restrict__ MLpart,
                                              __hip_bfloat16* __restrict__ rdb)
{
    const int t = threadIdx.x;
    const int row = blockIdx.x*64 + (t >> 2);
    const int c0 = (t & 3) * 32;
    float m[4], lv[4], a[4];
    float M = -INFINITY;
    #pragma unroll
    for (int i = 0; i < 4; i++) {
        m[i]  = MLpart[((size_t)row*4 + i)*2 + 0];
        lv[i] = MLpart[((size_t)row*4 + i)*2 + 1];
        M = fmaxf(M, m[i]);
    }
    float L = 0.f;
    #pragma unroll
    for (int i = 0; i < 4; i++) { a[i] = ex2(m[i] - M); L += a[i]*lv[i]; }   // log2 domain
    float invL = 1.f / L;
    #pragma unroll
    for (int i = 0; i < 4; i++) a[i] *= invL;
    unsigned short* dst = (unsigned short*)rdb + (size_t)row*128 + c0;
    #pragma unroll
    for (int j = 0; j < 8; j++) {
        float acc0=0.f, acc1=0.f, acc2=0.f, acc3=0.f;
        #pragma unroll
        for (int i = 0; i < 4; i++) {
            u16x4 x = ((const u16x4*)(Opart + ((size_t)row*4 + i)*128 + c0))[j];
            acc0 += a[i]*b2f(x[0]); acc1 += a[i]*b2f(x[1]);
            acc2 += a[i]*b2f(x[2]); acc3 += a[i]*b2f(x[3]);
        }
        u16x4 o = { bfu(acc0), bfu(acc1), bfu(acc2), bfu(acc3) };
        ((u16x4*)dst)[j] = o;
    }
}

// ---------------- K3: fused GRU (MFMA, LDS-staged, gi0-precomputed) ----------------
__global__ __launch_bounds__(256, 4) void k_gru(const float* __restrict__ gi0,
                                                const __hip_bfloat16* __restrict__ rdb,
                                                const __hip_bfloat16* __restrict__ regsb,
                                                const float* __restrict__ regs,
                                                const __hip_bfloat16* __restrict__ Wihb,
                                                const float* __restrict__ bih,
                                                const __hip_bfloat16* __restrict__ Whhb,
                                                const float* __restrict__ bhh,
                                                float* __restrict__ newregs,
                                                __hip_bfloat16* __restrict__ nregsb)
{
    __shared__ __hip_bfloat16 At[2][64][32];
    __shared__ __hip_bfloat16 Bt[2][192][32];
    const int t = threadIdx.x, w = t >> 6, l = t & 63;
    const int lg = l >> 4, ll = l & 15;
    const int m0 = blockIdx.x*64;
    const int n0 = blockIdx.y*64;
    const int batch = blockIdx.x >> 4;
    const short* Rd = (const short*)rdb;
    const short* Hb = (const short*)regsb;
    const short* Wi = (const short*)Wihb;
    const short* Wh = (const short*)Whhb;

    f32x4 aR[4], aZ[4], aNi[4], aNh[4];
    #pragma unroll
    for (int c = 0; c < 4; c++) {
        int o = n0 + c*16 + ll;
        float gR = gi0[(size_t)batch*768 + o];
        float gZ = gi0[(size_t)batch*768 + 256 + o];
        float gN = gi0[(size_t)batch*768 + 512 + o];
        aR[c]  = (f32x4){gR,gR,gR,gR};
        aZ[c]  = (f32x4){gZ,gZ,gZ,gZ};
        aNi[c] = (f32x4){gN,gN,gN,gN};
        aNh[c] = (f32x4){0,0,0,0};
    }

    const int aci = (w << 6) + l;
    const int arow_s = aci >> 2, acc_s = aci & 3;
    const int agc = acc_s ^ ((arow_s >> 1) & 3);
    const char* aSrcA = (const char*)(Rd + (size_t)(m0+arow_s)*MD) + agc*16;
    const char* aSrcB = (const char*)(Hb + (size_t)(m0+arow_s)*RS) + agc*16;
    const char* bSrcA0; const char* bSrcA1; const char* bSrcA2;
    const char* bSrcB0; const char* bSrcB1; const char* bSrcB2;
    {
        int ci, row, cc, gc, g, col;
        ci = w*192 + 0*64 + l; row = ci >> 2; cc = ci & 3; gc = cc ^ ((row >> 1) & 3);
        g = row >> 6; col = row & 63;
        bSrcA0 = (const char*)(Wi + (size_t)(g*RS + n0 + col)*GRUIN + INS) + gc*16;
        bSrcB0 = (const char*)(Wh + (size_t)(g*RS + n0 + col)*RS) + gc*16;
        ci = w*192 + 1*64 + l; row = ci >> 2; cc = ci & 3; gc = cc ^ ((row >> 1) & 3);
        g = row >> 6; col = row & 63;
        bSrcA1 = (const char*)(Wi + (size_t)(g*RS + n0 + col)*GRUIN + INS) + gc*16;
        bSrcB1 = (const char*)(Wh + (size_t)(g*RS + n0 + col)*RS) + gc*16;
        ci = w*192 + 2*64 + l; row = ci >> 2; cc = ci & 3; gc = cc ^ ((row >> 1) & 3);
        g = row >> 6; col = row & 63;
        bSrcA2 = (const char*)(Wi + (size_t)(g*RS + n0 + col)*GRUIN + INS) + gc*16;
        bSrcB2 = (const char*)(Wh + (size_t)(g*RS + n0 + col)*RS) + gc*16;
    }

    const int NITA = 4, NIT = 12;
    auto stage = [&](int buf, int it) {
        char* abase = (char*)(&At[buf][0][0]) + (size_t)(w << 6)*16;
        char* bbase = (char*)(&Bt[buf][0][0]) + (size_t)(w*192)*16;
        const char *as, *b0, *b1, *b2;
        if (it < NITA) {
            int off = it*64;
            as = aSrcA + off; b0 = bSrcA0 + off; b1 = bSrcA1 + off; b2 = bSrcA2 + off;
        } else {
            int off = (it - NITA)*64;
            as = aSrcB + off; b0 = bSrcB0 + off; b1 = bSrcB1 + off; b2 = bSrcB2 + off;
        }
        gload16(as, abase);
        gload16(b0, bbase);
        gload16(b1, bbase + 64*16);
        gload16(b2, bbase + 128*16);
    };

    stage(0, 0);
    asm volatile("s_waitcnt vmcnt(0)" ::: "memory");
    __syncthreads();
    int cur = 0;
    const int arow = (w << 4) + ll;
    const int aswz = ((lg ^ ((arow >> 1) & 3)) << 4);
    for (int it = 0; it < NIT; ++it) {
        if (it + 1 < NIT) stage(cur ^ 1, it + 1);
        const char* ab = (const char*)(&At[cur][0][0]);
        const char* bb = (const char*)(&Bt[cur][0][0]);
        bf16x8 af = *(const bf16x8*)(ab + arow*64 + aswz);
        if (it < NITA) {
            #pragma unroll
            for (int c = 0; c < 4; c++) {
                int r0 = c*16 + ll;
                int sw = ((lg ^ ((r0 >> 1) & 3)) << 4);
                bf16x8 bR = *(const bf16x8*)(bb + (size_t)r0*64 + sw);
                bf16x8 bZ = *(const bf16x8*)(bb + (size_t)(r0 + 64)*64 + sw);
                bf16x8 bN = *(const bf16x8*)(bb + (size_t)(r0 + 128)*64 + sw);
                aR[c]  = __builtin_amdgcn_mfma_f32_16x16x32_bf16(af, bR, aR[c],  0, 0, 0);
                aZ[c]  = __builtin_amdgcn_mfma_f32_16x16x32_bf16(af, bZ, aZ[c],  0, 0, 0);
                aNi[c] = __builtin_amdgcn_mfma_f32_16x16x32_bf16(af, bN, aNi[c], 0, 0, 0);
            }
        } else {
            #pragma unroll
            for (int c = 0; c < 4; c++) {
                int r0 = c*16 + ll;
                int sw = ((lg ^ ((r0 >> 1) & 3)) << 4);
                bf16x8 bR = *(const bf16x8*)(bb + (size_t)r0*64 + sw);
                bf16x8 bZ = *(const bf16x8*)(bb + (size_t)(r0 + 64)*64 + sw);
                bf16x8 bN = *(const bf16x8*)(bb + (size_t)(r0 + 128)*64 + sw);
                aR[c]  = __builtin_amdgcn_mfma_f32_16x16x32_bf16(af, bR, aR[c],  0, 0, 0);
                aZ[c]  = __builtin_amdgcn_mfma_f32_16x16x32_bf16(af, bZ, aZ[c],  0, 0, 0);
                aNh[c] = __builtin_amdgcn_mfma_f32_16x16x32_bf16(af, bN, aNh[c], 0, 0, 0);
            }
        }
        asm volatile("s_waitcnt vmcnt(0)" ::: "memory");
        __syncthreads();
        cur ^= 1;
    }
    const int wm0 = m0 + (w << 4);
    #pragma unroll
    for (int c = 0; c < 4; c++) {
        int o = n0 + c*16 + ll;
        float bR = bih[o]        + bhh[o];
        float bZ = bih[o +   RS] + bhh[o +   RS];
        float bNi = bih[o + 2*RS];
        float bNh = bhh[o + 2*RS];
        #pragma unroll
        for (int r = 0; r < 4; r++) {
            int row = wm0 + lg*4 + r;
            float rr = sigf(aR[c][r] + bR);
            float zz = sigf(aZ[c][r] + bZ);
            float nn = tanhf(aNi[c][r] + bNi + rr*(aNh[c][r] + bNh));
            float cv = regs[(size_t)row*RS + o];
            float nv = (1.f - zz)*nn + zz*cv;
            newregs[(size_t)row*RS + o] = nv;
            nregsb[(size_t)row*RS + o] = __float2bfloat16(nv);
        }
    }
}

// ---------------- K4: output GEMM (MFMA, LDS-staged, 128-col tiles) ----------------
__global__ __launch_bounds__(256, 4) void k_out(const __hip_bfloat16* __restrict__ Ab,
                                                const __hip_bfloat16* __restrict__ Wb,
                                                const float* __restrict__ bias,
                                                float* __restrict__ out0)
{
    __shared__ __hip_bfloat16 At[2][64][32];
    __shared__ __hip_bfloat16 Bt[2][128][32];
    const int t = threadIdx.x, w = t >> 6, l = t & 63;
    const int lg = l >> 4, ll = l & 15;
    const int m0 = blockIdx.x*64;
    const int n0 = blockIdx.y*128;
    f32x4 acc[8];
    #pragma unroll
    for (int c = 0; c < 8; c++) acc[c] = (f32x4){0,0,0,0};

    const char* aSrc;
    {
        int row = t >> 2, cc = t & 3;
        int gc = cc ^ ((row >> 1) & 3);
        aSrc = (const char*)((const short*)Ab + (size_t)(m0+row)*RS) + gc*16;
    }
    const char* bSrc[2];
    #pragma unroll
    for (int j = 0; j < 2; j++) {
        int ci = w*128 + j*64 + l;
        int row = ci >> 2, cc = ci & 3;
        int gc = cc ^ ((row >> 1) & 3);
        bSrc[j] = (const char*)((const short*)Wb + (size_t)(n0+row)*RS) + gc*16;
    }

    auto stage = [&](int buf, int it) {
        int off = it*64;
        char* abase = (char*)(&At[buf][0][0]) + (size_t)(w << 6)*16;
        gload16(aSrc + off, abase);
        #pragma unroll
        for (int j = 0; j < 2; j++) {
            char* bbase = (char*)(&Bt[buf][0][0]) + (size_t)(w*128 + j*64)*16;
            gload16(bSrc[j] + off, bbase);
        }
    };

    stage(0, 0);
    asm volatile("s_waitcnt vmcnt(0)" ::: "memory");
    __syncthreads();
    int cur = 0;
    const int arow = (w << 4) + ll;
    const int aswz = ((lg ^ ((arow >> 1) & 3)) << 4);
    for (int it = 0; it < 8; ++it) {
        if (it + 1 < 8) stage(cur ^ 1, it + 1);
        const char* ab = (const char*)(&At[cur][0][0]);
        const char* bb = (const char*)(&Bt[cur][0][0]);
        bf16x8 af = *(const bf16x8*)(ab + arow*64 + aswz);
        #pragma unroll
        for (int c = 0; c < 8; c++) {
            int r0 = c*16 + ll;
            int sw = ((lg ^ ((r0 >> 1) & 3)) << 4);
            bf16x8 bf = *(const bf16x8*)(bb + (size_t)r0*64 + sw);
            acc[c] = __builtin_amdgcn_mfma_f32_16x16x32_bf16(af, bf, acc[c], 0, 0, 0);
        }
        asm volatile("s_waitcnt vmcnt(0)" ::: "memory");
        __syncthreads();
        cur ^= 1;
    }
    const int wm0 = m0 + (w << 4);
    #pragma unroll
    for (int c = 0; c < 8; c++) {
        int o = n0 + c*16 + ll;
        float bv = bias[o];
        #pragma unroll
        for (int r = 0; r < 4; r++) {
            int row = wm0 + lg*4 + r;
            out0[(size_t)row*INS + o] = acc[c][r] + bv;
        }
    }
}

extern "C" void kernel_launch(void* const* d_in, const int* in_sizes, int n_in,
                              void* d_out, int out_size, void* d_ws, size_t ws_size,
                              hipStream_t stream)
{
    const float* inp  = (const float*)d_in[0];
    const float* regs = (const float*)d_in[1];
    const float* mem  = (const float*)d_in[2];
    const float* Wih  = (const float*)d_in[3];
    const float* bih  = (const float*)d_in[4];
    const float* Whh  = (const float*)d_in[5];
    const float* bhh  = (const float*)d_in[6];
    const float* Wmmu = (const float*)d_in[7];
    const float* bmmu = (const float*)d_in[8];
    const float* Wout = (const float*)d_in[9];
    const float* bout = (const float*)d_in[10];
    float* out = (float*)d_out;

    char* ws = (char*)d_ws;
    __hip_bfloat16* qbf    = (__hip_bfloat16*)(ws);
    __hip_bfloat16* rdb    = (__hip_bfloat16*)(ws + ((size_t)4<<20));
    __hip_bfloat16* memB   = (__hip_bfloat16*)(ws + ((size_t)8<<20));
    __hip_bfloat16* memT   = (__hip_bfloat16*)(ws + ((size_t)24<<20));
    __hip_bfloat16* regsb  = (__hip_bfloat16*)(ws + ((size_t)40<<20));
    __hip_bfloat16* nregsb = (__hip_bfloat16*)(ws + ((size_t)48<<20));
    __hip_bfloat16* Wmmub  = (__hip_bfloat16*)(ws + ((size_t)56<<20));
    __hip_bfloat16* Wihb   = (__hip_bfloat16*)(ws + ((size_t)56<<20) + ( 1<<20));
    __hip_bfloat16* Whhb   = (__hip_bfloat16*)(ws + ((size_t)56<<20) + ( 2<<20));
    __hip_bfloat16* Woutb  = (__hip_bfloat16*)(ws + ((size_t)56<<20) + ( 3<<20));
    __hip_bfloat16* inpb   = (__hip_bfloat16*)(ws + ((size_t)56<<20) + ( 4<<20));
    float*          MLpart = (float*)(ws + ((size_t)61<<20));            // 512 KB
    float*          gi0    = (float*)(ws + ((size_t)61<<20) + (1<<19));  // 49 KB
    unsigned short* Opart  = (unsigned short*)(out + O_OUT);  // 16.7 MB bf16 in out0 region

    k_cvt5g<<<1017, 256, 0, stream>>>(Wmmu, (unsigned short*)Wmmub,
                                      Wih,  (unsigned short*)Wihb,
                                      Whh,  (unsigned short*)Whhb,
                                      Wout, (unsigned short*)Woutb,
                                      inp,  (unsigned short*)inpb, gi0);
    k_cvt<<<(4194304/4 + 255)/256, 256, 0, stream>>>(regs, (unsigned short*)regsb, 4194304/4);
    k_conv<<<B_*128, 256, 0, stream>>>(mem, memB, memT);

    dim3 g1(NROWS/64, 6);
    k_mmu<<<g1, 256, 0, stream>>>(regsb, Wmmub, bmmu, out, qbf);
    k_attn<<<512, 256, 0, stream>>>(qbf, memB, memT, Opart, MLpart);
    k_comb<<<NROWS/64, 256, 0, stream>>>(Opart, MLpart, rdb);
    dim3 g3(NROWS/64, 4);
    k_gru<<<g3, 256, 0, stream>>>(gi0, rdb, regsb, regs, Wihb, bih, Whhb, bhh,
                                  out + O_REGS, nregsb);
    dim3 g4(NROWS/64, 4);
    k_out<<<g4, 256, 0, stream>>>(nregsb, Woutb, bout, out);
}